// Round 4
// baseline (322.008 us; speedup 1.0000x reference)
//
#include <hip/hip_runtime.h>

typedef unsigned long long ull;
typedef float f4 __attribute__((ext_vector_type(4)));  // native vec: OK for nontemporal builtins

// 8 batches x 4096 seq = 32768 positions; 16 slots x 80 floats = 1280 out/pos.
// One wave handles 4 positions: lane = p*16 + slot hashes one (pos, slot) pair
// (no redundant hash work), then the copy phase issues ALL 20 float4 gathers
// before any store (4x the memory-level parallelism of the 1-pos/wave version).
// Stores are nontemporal: output is write-once, keep L2/L3 for table reuse.

__constant__ unsigned c_sz[16] = {
    6619u, 6637u, 6653u, 6659u, 6661u, 6673u, 6679u, 6689u,
    65521u, 65537u, 65539u, 65543u, 65551u, 65557u, 65563u, 65579u
};

// m = floor(2^64/d)+1 (= ~0ull/d + 1 for d not dividing 2^64).
// Exact quotient for h < 2^47 since h*(m*d - 2^64) <= 2^47 * d < 2^64.
constexpr ull MG(unsigned d) { return ~0ULL / d + 1ULL; }

__constant__ ull c_mg[16] = {
    MG(6619u), MG(6637u), MG(6653u), MG(6659u),
    MG(6661u), MG(6673u), MG(6679u), MG(6689u),
    MG(65521u), MG(65537u), MG(65539u), MG(65543u),
    MG(65551u), MG(65557u), MG(65563u), MG(65579u)
};

__global__ __launch_bounds__(256, 3)  // allow ~170 VGPR: 20 float4 live + addr calc, no spill
void engram_kernel(const int* __restrict__ ids,
                   const int* __restrict__ seeds,
                   const float* __restrict__ t0,  const float* __restrict__ t1,
                   const float* __restrict__ t2,  const float* __restrict__ t3,
                   const float* __restrict__ t4,  const float* __restrict__ t5,
                   const float* __restrict__ t6,  const float* __restrict__ t7,
                   const float* __restrict__ t8,  const float* __restrict__ t9,
                   const float* __restrict__ t10, const float* __restrict__ t11,
                   const float* __restrict__ t12, const float* __restrict__ t13,
                   const float* __restrict__ t14, const float* __restrict__ t15,
                   float* __restrict__ out)
{
    __shared__ const float* tab[16];
    if (threadIdx.x == 0) {
        tab[0]=t0;   tab[1]=t1;   tab[2]=t2;   tab[3]=t3;
        tab[4]=t4;   tab[5]=t5;   tab[6]=t6;   tab[7]=t7;
        tab[8]=t8;   tab[9]=t9;   tab[10]=t10; tab[11]=t11;
        tab[12]=t12; tab[13]=t13; tab[14]=t14; tab[15]=t15;
    }
    __syncthreads();

    const int wave = threadIdx.x >> 6;
    const int lane = threadIdx.x & 63;
    // 16 positions per block (4 waves x 4 positions); grid = 2048 -> 32768 pos
    const int basePos = (blockIdx.x << 4) + (wave << 2);

    // ---- hash phase: lane l -> (p = l>>4, slot = l&15) ----
    const int p    = lane >> 4;
    const int slot = lane & 15;
    const int head = slot & 7;
    const int pos  = basePos + p;
    const int b = pos >> 12;
    const int s = pos & 4095;

    const int* row = ids + (b << 12);
    const int id0  = row[s];
    const int idm1 = (s >= 1) ? row[s - 1] : 0;   // left zero-pad per _ngrams

    const ull sa = (ull)(unsigned)seeds[head];        // seed row 0
    const ull sb = (ull)(unsigned)seeds[8 + head];    // seed row 1
    ull h;
    if (slot < 8) {
        // bigram: [ids[s-1], ids[s]] . seeds rows 0,1
        h = ((ull)(unsigned)idm1 * sa) ^ ((ull)(unsigned)id0 * sb);
    } else {
        // trigram: [ids[s-2], ids[s-1], ids[s]] . seeds rows 0,1,2
        const int idm2 = (s >= 2) ? row[s - 2] : 0;
        const ull sc = (ull)(unsigned)seeds[16 + head];
        h = ((ull)(unsigned)idm2 * sa) ^ ((ull)(unsigned)idm1 * sb)
            ^ ((ull)(unsigned)id0 * sc);
    }
    // products < 2^47, xor >= 0 -> unsigned mod == jnp floored mod.
    // Magic-multiply division (exact, see MG proof); 1-instr fixup for safety.
    const unsigned sz = c_sz[slot];
    const ull q = __umul64hi(h, c_mg[slot]);
    ull r = h - q * (ull)sz;
    if ((long long)r < 0) r += sz;
    const int boff = (int)r * 320;                // byte offset of row in its table

    // ---- copy phase: 4 pos x 320 float4 = 1280 float4; 20 per lane ----
    // Issue all 20 gathers first (20 x 16B in flight per lane), then store.
    f4 v[20];
    #pragma unroll
    for (int j = 0; j < 20; ++j) {
        const unsigned f   = (unsigned)lane + ((unsigned)j << 6);  // 0..1279
        const unsigned p2  = f / 320u;            // which of the 4 positions
        const unsigned rem = f - p2 * 320u;
        const unsigned gs  = rem / 20u;           // slot 0..15
        const unsigned off = rem - gs * 20u;      // float4 within 80-float row
        const int srcLane  = (int)((p2 << 4) + gs);
        const int rb = __shfl(boff, srcLane, 64);
        const char* srcp = (const char*)tab[gs] + (unsigned)rb + (off << 4);
        v[j] = *(const f4*)srcp;
    }

    f4* dst = (f4*)out + (size_t)basePos * 320;
    #pragma unroll
    for (int j = 0; j < 20; ++j) {
        __builtin_nontemporal_store(v[j], dst + lane + (j << 6));
    }
}

extern "C" void kernel_launch(void* const* d_in, const int* in_sizes, int n_in,
                              void* d_out, int out_size, void* d_ws, size_t ws_size,
                              hipStream_t stream) {
    const int* ids   = (const int*)d_in[0];
    const int* seeds = (const int*)d_in[1];
    const float* t[16];
    for (int i = 0; i < 16; ++i) t[i] = (const float*)d_in[2 + i];

    engram_kernel<<<dim3(2048), dim3(256), 0, stream>>>(
        ids, seeds,
        t[0], t[1], t[2], t[3], t[4], t[5], t[6], t[7],
        t[8], t[9], t[10], t[11], t[12], t[13], t[14], t[15],
        (float*)d_out);
}